// Round 6
// baseline (2137.262 us; speedup 1.0000x reference)
//
#include <hip/hip_runtime.h>

constexpr int NB = 2;
constexpr int NC = 64;
constexpr int NH = 192;
constexpr int NW = 192;
constexpr int NK = 7;
constexpr int NHW = NH * NW;          // 36864
constexpr int NPIX = NB * NHW;        // 73728
constexpr float EPS = 1e-6f;

// ---------------------------------------------------------------------------
// Kernel 1 (v3): R4 body at 512 threads. Same 128-px tile, same LDS layout,
// same W staging, same inner loop; 8 waves/block -> 4.5 waves/SIMD (2x R4's
// TLP). __launch_bounds__(512,4) hard-caps VGPR at 128 so the allocator
// cannot repeat R9's hoist-to-256-then-spill. acc = 8 outs x 4 px (32 regs).
// Channel accumulation order r=0..64 unchanged -> identical logits.
// ---------------------------------------------------------------------------
__global__ __launch_bounds__(512, 4) void qk_gemm(
    const float* __restrict__ g, const float* __restrict__ cd,
    const float* __restrict__ mask,
    const float* __restrict__ ln_w, const float* __restrict__ ln_b,
    const float* __restrict__ conv_w, const float* __restrict__ conv_b,
    float* __restrict__ qbuf, float* __restrict__ kbuf)
{
    __shared__ float Z[65][128];       // 33.3 KB
    __shared__ float WTc[33][128];     // 16.9 KB  (total 50.2 KB)

    int tid = threadIdx.x;
    int p0 = blockIdx.x * 128;
    int b  = p0 / NHW;
    int hw0 = p0 - b * NHW;

    // ---- layernorm: 4 threads/px, 16 channels each, 2-step shfl reduce ----
    int px = tid >> 2;          // 0..127
    int qu = tid & 3;           // channel quad 0..3 (16 ch each)
    const float* gp = g + (size_t)(b * NC + qu * 16) * NHW + (hw0 + px);
    float vals[16];
    float s = 0.f, sq = 0.f;
#pragma unroll
    for (int j = 0; j < 16; ++j) {
        float v = gp[(size_t)j * NHW];
        vals[j] = v; s += v; sq += v * v;
    }
    s  += __shfl_xor(s, 1);  sq += __shfl_xor(sq, 1);
    s  += __shfl_xor(s, 2);  sq += __shfl_xor(sq, 2);
    float mu   = s * (1.f / 64.f);
    float rstd = rsqrtf(sq * (1.f / 64.f) - mu * mu + EPS);
#pragma unroll
    for (int j = 0; j < 16; ++j) {
        int c = qu * 16 + j;
        Z[c][px] = (vals[j] - mu) * rstd * ln_w[c] + ln_b[c];
    }
    if (qu == 3) Z[64][px] = cd[p0 + px];

    // ---- GEMM: 128 outs x 128 px; thread = 8 outs x 4 px ----
    int og = tid >> 5;          // 0..15 -> outs 8*og..8*og+7
    int pg = tid & 31;          // 0..31 -> px 4*pg..4*pg+3
    float acc[8][4];
#pragma unroll
    for (int oi = 0; oi < 8; ++oi)
#pragma unroll
        for (int pj = 0; pj < 4; ++pj) acc[oi][pj] = 0.f;

    for (int cc = 0; cc < 65; cc += 33) {
        int nr = (65 - cc < 33) ? (65 - cc) : 33;
        __syncthreads();
        if (tid < 128) {
            int o = tid;
            for (int r = 0; r < nr; ++r)
                WTc[r][o] = conv_w[o * 65 + cc + r];
        }
        __syncthreads();
        for (int r = 0; r < nr; ++r) {
            float4 w0 = *(const float4*)&WTc[r][8 * og];
            float4 w1 = *(const float4*)&WTc[r][8 * og + 4];
            float4 z0 = *(const float4*)&Z[cc + r][4 * pg];
            float w8[8] = {w0.x, w0.y, w0.z, w0.w, w1.x, w1.y, w1.z, w1.w};
            float z4[4] = {z0.x, z0.y, z0.z, z0.w};
#pragma unroll
            for (int oi = 0; oi < 8; ++oi)
#pragma unroll
                for (int pj = 0; pj < 4; ++pj)
                    acc[oi][pj] = fmaf(w8[oi], z4[pj], acc[oi][pj]);
        }
    }

    // ---- epilogue ----
    int o0  = og * 8;
    int pxb = pg * 4;
    float4 ba = *(const float4*)&conv_b[o0];
    float4 bb = *(const float4*)&conv_b[o0 + 4];
    float bia[8] = {ba.x, ba.y, ba.z, ba.w, bb.x, bb.y, bb.z, bb.w};
    bool isq = (o0 < 64);
    float m4[4];
    if (!isq) {
        float4 ma = *(const float4*)&mask[p0 + pxb];
        m4[0]=ma.x; m4[1]=ma.y; m4[2]=ma.z; m4[3]=ma.w;
    }
    float* base = isq ? (qbuf + (size_t)(b * NC + o0) * NHW + hw0 + pxb)
                      : (kbuf + (size_t)(b * NC + o0 - 64) * NHW + hw0 + pxb);
#pragma unroll
    for (int oi = 0; oi < 8; ++oi) {
        float v[4];
#pragma unroll
        for (int pj = 0; pj < 4; ++pj) {
            float t = acc[oi][pj] + bia[oi];
            v[pj] = isq ? t : t * m4[pj];
        }
        float* dst = base + (size_t)oi * NHW;
        *(float4*)&dst[0] = make_float4(v[0], v[1], v[2], v[3]);
    }
}

// ---------------------------------------------------------------------------
// Kernel 2 (v8, UNCHANGED from R8 — verified ~39 µs): 2-pixel horizontal
// blocking, 4 channel-quarter waves, conflict-free xch combine, XCD swizzle.
// ---------------------------------------------------------------------------
struct TrueC  { static constexpr bool value = true;  };
struct FalseC { static constexpr bool value = false; };

__global__ __launch_bounds__(256) void attn_tile(
    const float* __restrict__ qbuf, const float* __restrict__ kbuf,
    const float* __restrict__ cd, const float* __restrict__ sd,
    const float* __restrict__ mask, const float* __restrict__ rpb,
    float* __restrict__ out_cd, float* __restrict__ out_mask)
{
    __shared__ float kst[4][2][350];   // 11.2 KB: 4 waves x 2 bufs x 14x25
    __shared__ float xch[49][2][64];   // 24.5 KB, conflict-free combine
    __shared__ float cdt[350];         // 14 x 22 @ pitch 25
    __shared__ float mt [350];
    __shared__ float rpbt[169];        // total ~38.8 KB

    int tid  = threadIdx.x;
    int g    = tid >> 6;       // channel quarter 0..3 (16 ch each)
    int lane = tid & 63;
    int tx   = lane & 7;       // col-pair index
    int ty   = lane >> 3;      // row 0..7

    // XCD swizzle (proven 4x FETCH cut): contiguous 72-tile slab per XCD.
    int bid = blockIdx.x;
    int swz = (bid & 7) * 72 + (bid >> 3);
    int bw = swz % 12;
    int t2 = swz / 12;
    int bh = t2 % 24;
    int b  = t2 / 24;
    int w0 = bw * 16, h0 = bh * 8;

    int h   = h0 + ty;
    int wpx = w0 + 2 * tx;                      // pixel0; pixel1 = wpx+1
    int rs  = min(max(h - 3, 0), NH - NK);
    int cs0 = min(max(wpx - 3, 0), NW - NK);
    int cs1 = min(max(wpx - 2, 0), NW - NK);
    int d1  = cs1 - cs0;                        // 0 or 1; 1 for bw in 1..10
    int ktb = (rs - (h0 - 3)) * 25 + (cs0 - (w0 - 3));

    // ---- block-level cd/mask/rpb staging (14x22 tile, 308 elems) ----
    const float* cdb = cd   + (size_t)b * NHW;
    const float* msb = mask + (size_t)b * NHW;
    for (int e = tid; e < 308; e += 256) {
        int r = e / 22, c = e - r * 22;
        int gr = min(max(h0 - 3 + r, 0), NH - 1);
        int gc = min(max(w0 - 3 + c, 0), NW - 1);
        cdt[r * 25 + c] = cdb[gr * NW + gc];
        mt [r * 25 + c] = msb[gr * NW + gc];
    }
    if (tid < 169) rpbt[tid] = rpb[tid];

    // ---- k staging slots: 308 elems (14x22), 5 rounds of 64 ----
    int soff[5], slds[5];
#pragma unroll
    for (int s = 0; s < 5; ++s) {
        int e = lane + 64 * s;
        int r = e / 22, c = e - r * 22;
        int gr = min(max(h0 - 3 + r, 0), NH - 1);
        int gc = min(max(w0 - 3 + c, 0), NW - 1);
        bool act = e < 308;
        soff[s] = act ? (gr * NW + gc) : 0;     // safe addr for inactive
        slds[s] = act ? (r * 25 + c) : 348;     // dummy slot for inactive
    }

    const float* kb = kbuf + (size_t)(b * NC + g * 16) * NHW;
    const float* qb = qbuf + (size_t)(b * NC + g * 16) * NHW + h * NW + wpx;

    float at0[49], at1[49];
#pragma unroll
    for (int n = 0; n < 49; ++n) { at0[n] = 0.f; at1[n] = 0.f; }

    float* k0 = &kst[g][0][0];
    float* k1 = &kst[g][1][0];

    auto run = [&](auto edgec) {
        constexpr bool EDGE = decltype(edgec)::value;
        float st[5];
#pragma unroll
        for (int s = 0; s < 5; ++s) st[s] = kb[soff[s]];
#pragma unroll
        for (int s = 0; s < 5; ++s) k0[slds[s]] = st[s];
        float2 qA = *(const float2*)qb;
        float2 qB = *(const float2*)(qb + NHW);
        for (int i = 0; i < 16; ++i) {
            if (i + 1 < 16) {
                const float* kb2 = kb + (size_t)(i + 1) * NHW;
#pragma unroll
                for (int s = 0; s < 5; ++s) st[s] = kb2[soff[s]];
            }
            float2 q = qA; qA = qB;
            if (i + 2 < 16) qB = *(const float2*)(qb + (size_t)(i + 2) * NHW);
            const float* kt = ((i & 1) ? k1 : k0) + ktb;
#pragma unroll
            for (int r = 0; r < 7; ++r) {
                const float* kr = kt + r * 25;
                float v[8];
#pragma unroll
                for (int j = 0; j < 8; ++j) v[j] = kr[j];
#pragma unroll
                for (int j = 0; j < 7; ++j)
                    at0[r * 7 + j] = fmaf(q.x, v[j], at0[r * 7 + j]);
#pragma unroll
                for (int j = 0; j < 7; ++j) {
                    float u;
                    if constexpr (EDGE) u = d1 ? v[j + 1] : v[j];
                    else                u = v[j + 1];
                    at1[r * 7 + j] = fmaf(q.y, u, at1[r * 7 + j]);
                }
            }
            if (i + 1 < 16) {
                float* nk = (i & 1) ? k0 : k1;
#pragma unroll
                for (int s = 0; s < 5; ++s) nk[slds[s]] = st[s];
            }
        }
    };
    if (bw == 0 || bw == 11) run(TrueC{}); else run(FalseC{});

    // ---- combine 4 quarters via xch[n][pp][lane] (conflict-free) ----
    __syncthreads();                       // also publishes cdt/mt/rpbt
    if (g == 3) {
#pragma unroll
        for (int n = 0; n < 49; ++n) {
            xch[n][0][lane] = at0[n]; xch[n][1][lane] = at1[n];
        }
    }
    __syncthreads();
    if (g == 2) {
#pragma unroll
        for (int n = 0; n < 49; ++n) {
            xch[n][0][lane] += at0[n]; xch[n][1][lane] += at1[n];
        }
    }
    __syncthreads();
    if (g == 0) {
#pragma unroll
        for (int n = 0; n < 49; ++n) {
            xch[n][0][lane] += at0[n]; xch[n][1][lane] += at1[n];
        }
    }
    __syncthreads();
    int pr  = 6 - (h - rs);
    int pc0 = 6 - (wpx - cs0);
    int pc1 = 6 - (wpx + 1 - cs1);
    if (g == 1) {
#pragma unroll
        for (int n = 0; n < 49; ++n) {
            at0[n] += xch[n][0][lane]; at1[n] += xch[n][1][lane];
        }
#pragma unroll
        for (int r = 0; r < 7; ++r)
#pragma unroll
            for (int j = 0; j < 7; ++j) {
                at0[r * 7 + j] += rpbt[(pr + r) * 13 + pc0 + j];
                at1[r * 7 + j] += rpbt[(pr + r) * 13 + pc1 + j];
            }
#pragma unroll
        for (int n = 0; n < 49; ++n) {
            xch[n][0][lane] = at0[n]; xch[n][1][lane] = at1[n];
        }
    }
    __syncthreads();
    if (g == 0) {
#pragma unroll
        for (int n = 0; n < 49; ++n) {
            at0[n] = xch[n][0][lane]; at1[n] = xch[n][1][lane];
        }
    }
    if (g >= 2) return;

    // ---- softmax (quarters 0/1 hold identical full logits) ----
    float mx0 = -1e30f, mx1 = -1e30f;
#pragma unroll
    for (int n = 0; n < 49; ++n) {
        mx0 = fmaxf(mx0, at0[n]); mx1 = fmaxf(mx1, at1[n]);
    }
    float sm0 = 0.f, sm1 = 0.f;
#pragma unroll
    for (int n = 0; n < 49; ++n) {
        at0[n] = __expf(at0[n] - mx0); sm0 += at0[n];
        at1[n] = __expf(at1[n] - mx1); sm1 += at1[n];
    }

    // ---- aggregate: quarter 0 -> cd, quarter 1 -> mask (shared window) ----
    const float* vt = (g ? mt : cdt) + ktb;
    float sv0 = 0.f, sv1 = 0.f;
#pragma unroll
    for (int r = 0; r < 7; ++r) {
        const float* vr = vt + r * 25;
        float v[8];
#pragma unroll
        for (int j = 0; j < 8; ++j) v[j] = vr[j];
#pragma unroll
        for (int j = 0; j < 7; ++j) {
            sv0 = fmaf(at0[r * 7 + j], v[j], sv0);
            float u = d1 ? v[j + 1] : v[j];
            sv1 = fmaf(at1[r * 7 + j], u, sv1);
        }
    }
    sv0 /= sm0; sv1 /= sm1;

    int p = b * NHW + h * NW + wpx;
    float2 sdv = *(const float2*)(sd + p);
    int ci = (ty + 3) * 25 + (2 * tx + 3);
    float mc0 = mt[ci], mc1 = mt[ci + 1];
    if (g == 0) {
        float cdc0 = cdt[ci], cdc1 = cdt[ci + 1];
        float co0 = sv0 * mc0 + cdc0 * (1.f - mc0);
        float co1 = sv1 * mc1 + cdc1 * (1.f - mc1);
        if (sdv.x > 0.f) co0 = sdv.x;
        if (sdv.y > 0.f) co1 = sdv.y;
        *(float2*)(out_cd + p) = make_float2(co0, co1);
    } else {
        float o0 = (sdv.x > 0.f) ? mc0 : sv0;
        float o1 = (sdv.y > 0.f) ? mc1 : sv1;
        *(float2*)(out_mask + p) = make_float2(o0, o1);
    }
}

extern "C" void kernel_launch(void* const* d_in, const int* in_sizes, int n_in,
                              void* d_out, int out_size, void* d_ws, size_t ws_size,
                              hipStream_t stream) {
    const float* g      = (const float*)d_in[0];
    const float* cd     = (const float*)d_in[1];
    const float* sd     = (const float*)d_in[2];
    const float* mask   = (const float*)d_in[3];
    const float* ln_w   = (const float*)d_in[4];
    const float* ln_b   = (const float*)d_in[5];
    const float* conv_w = (const float*)d_in[6];
    const float* conv_b = (const float*)d_in[7];
    const float* rpb    = (const float*)d_in[8];

    float* out  = (float*)d_out;                 // [cd_out | mask_out]
    float* qbuf = (float*)d_ws;                  // NB*NC*NHW floats
    float* kbuf = qbuf + (size_t)NB * NC * NHW;  // NB*NC*NHW floats

    qk_gemm<<<dim3(NPIX / 128), dim3(512), 0, stream>>>(
        g, cd, mask, ln_w, ln_b, conv_w, conv_b, qbuf, kbuf);
    attn_tile<<<dim3(NB * 24 * 12), dim3(256), 0, stream>>>(
        qbuf, kbuf, cd, sd, mask, rpb, out, out + NPIX);
}

// Round 7
// 140.083 us; speedup vs baseline: 15.2571x; 15.2571x over previous
//
#include <hip/hip_runtime.h>

constexpr int NB = 2;
constexpr int NC = 64;
constexpr int NH = 192;
constexpr int NW = 192;
constexpr int NK = 7;
constexpr int NHW = NH * NW;          // 36864
constexpr int NPIX = NB * NHW;        // 73728
constexpr float EPS = 1e-6f;

// ---------------------------------------------------------------------------
// Kernel 1: layernorm + 1x1 conv as LDS-tiled GEMM.  Exact R4 body (256
// threads, 128-px tile, acc 8x8 — the proven 68-VGPR allocator-stable shape).
// ONLY change vs R4: WTc staging parallelized across all 256 threads
// (was 128 threads x serial 33-iter loop) — pure LDS-fill redistribution
// between the same two barriers; GEMM arithmetic untouched.
// ---------------------------------------------------------------------------
__global__ __launch_bounds__(256) void qk_gemm(
    const float* __restrict__ g, const float* __restrict__ cd,
    const float* __restrict__ mask,
    const float* __restrict__ ln_w, const float* __restrict__ ln_b,
    const float* __restrict__ conv_w, const float* __restrict__ conv_b,
    float* __restrict__ qbuf, float* __restrict__ kbuf)
{
    __shared__ float Z[65][128];
    __shared__ float WTc[33][128];

    int tid = threadIdx.x;
    int p0 = blockIdx.x * 128;
    int b  = p0 / NHW;
    int hw0 = p0 - b * NHW;

    int px = tid >> 1;
    int hf = tid & 1;
    const float* gp = g + (size_t)(b * NC + hf * 32) * NHW + (hw0 + px);
    float vals[32];
    float s = 0.f, sq = 0.f;
#pragma unroll
    for (int j = 0; j < 32; ++j) {
        float v = gp[(size_t)j * NHW];
        vals[j] = v; s += v; sq += v * v;
    }
    s  += __shfl_xor(s, 1);
    sq += __shfl_xor(sq, 1);
    float mu   = s * (1.f / 64.f);
    float rstd = rsqrtf(sq * (1.f / 64.f) - mu * mu + EPS);
#pragma unroll
    for (int j = 0; j < 32; ++j) {
        int c = hf * 32 + j;
        Z[c][px] = (vals[j] - mu) * rstd * ln_w[c] + ln_b[c];
    }
    if (hf) Z[64][px] = cd[p0 + px];

    int og = tid >> 4;
    int pg = tid & 15;
    float acc[8][8];
#pragma unroll
    for (int oi = 0; oi < 8; ++oi)
#pragma unroll
        for (int pj = 0; pj < 8; ++pj) acc[oi][pj] = 0.f;

    for (int cc = 0; cc < 65; cc += 33) {
        int nr = (65 - cc < 33) ? (65 - cc) : 33;
        __syncthreads();
        for (int e = tid; e < nr * 128; e += 256) {
            int r = e >> 7, o = e & 127;
            WTc[r][o] = conv_w[o * 65 + cc + r];
        }
        __syncthreads();
        for (int r = 0; r < nr; ++r) {
            float4 w0 = *(const float4*)&WTc[r][8 * og];
            float4 w1 = *(const float4*)&WTc[r][8 * og + 4];
            float4 z0 = *(const float4*)&Z[cc + r][8 * pg];
            float4 z1 = *(const float4*)&Z[cc + r][8 * pg + 4];
            float w8[8] = {w0.x, w0.y, w0.z, w0.w, w1.x, w1.y, w1.z, w1.w};
            float z8[8] = {z0.x, z0.y, z0.z, z0.w, z1.x, z1.y, z1.z, z1.w};
#pragma unroll
            for (int oi = 0; oi < 8; ++oi)
#pragma unroll
                for (int pj = 0; pj < 8; ++pj)
                    acc[oi][pj] = fmaf(w8[oi], z8[pj], acc[oi][pj]);
        }
    }

    int o0  = og * 8;
    int pxb = pg * 8;
    float4 ba = *(const float4*)&conv_b[o0];
    float4 bb = *(const float4*)&conv_b[o0 + 4];
    float bia[8] = {ba.x, ba.y, ba.z, ba.w, bb.x, bb.y, bb.z, bb.w};
    bool isq = (o0 < 64);
    float m8[8];
    if (!isq) {
        float4 ma = *(const float4*)&mask[p0 + pxb];
        float4 mc = *(const float4*)&mask[p0 + pxb + 4];
        m8[0]=ma.x; m8[1]=ma.y; m8[2]=ma.z; m8[3]=ma.w;
        m8[4]=mc.x; m8[5]=mc.y; m8[6]=mc.z; m8[7]=mc.w;
    }
    float* base = isq ? (qbuf + (size_t)(b * NC + o0) * NHW + hw0 + pxb)
                      : (kbuf + (size_t)(b * NC + o0 - 64) * NHW + hw0 + pxb);
#pragma unroll
    for (int oi = 0; oi < 8; ++oi) {
        float v[8];
#pragma unroll
        for (int pj = 0; pj < 8; ++pj) {
            float t = acc[oi][pj] + bia[oi];
            v[pj] = isq ? t : t * m8[pj];
        }
        float* dst = base + (size_t)oi * NHW;
        *(float4*)&dst[0] = make_float4(v[0], v[1], v[2], v[3]);
        *(float4*)&dst[4] = make_float4(v[4], v[5], v[6], v[7]);
    }
}

// ---------------------------------------------------------------------------
// Kernel 2 (v8, byte-identical to R8 — measured ~39 µs): 2-pixel horizontal
// blocking, 4 channel-quarter waves, conflict-free xch combine, XCD swizzle.
// ---------------------------------------------------------------------------
struct TrueC  { static constexpr bool value = true;  };
struct FalseC { static constexpr bool value = false; };

__global__ __launch_bounds__(256) void attn_tile(
    const float* __restrict__ qbuf, const float* __restrict__ kbuf,
    const float* __restrict__ cd, const float* __restrict__ sd,
    const float* __restrict__ mask, const float* __restrict__ rpb,
    float* __restrict__ out_cd, float* __restrict__ out_mask)
{
    __shared__ float kst[4][2][350];   // 11.2 KB: 4 waves x 2 bufs x 14x25
    __shared__ float xch[49][2][64];   // 24.5 KB, conflict-free combine
    __shared__ float cdt[350];         // 14 x 22 @ pitch 25
    __shared__ float mt [350];
    __shared__ float rpbt[169];        // total ~38.8 KB

    int tid  = threadIdx.x;
    int g    = tid >> 6;       // channel quarter 0..3 (16 ch each)
    int lane = tid & 63;
    int tx   = lane & 7;       // col-pair index
    int ty   = lane >> 3;      // row 0..7

    // XCD swizzle (proven 4x FETCH cut): contiguous 72-tile slab per XCD.
    int bid = blockIdx.x;
    int swz = (bid & 7) * 72 + (bid >> 3);
    int bw = swz % 12;
    int t2 = swz / 12;
    int bh = t2 % 24;
    int b  = t2 / 24;
    int w0 = bw * 16, h0 = bh * 8;

    int h   = h0 + ty;
    int wpx = w0 + 2 * tx;                      // pixel0; pixel1 = wpx+1
    int rs  = min(max(h - 3, 0), NH - NK);
    int cs0 = min(max(wpx - 3, 0), NW - NK);
    int cs1 = min(max(wpx - 2, 0), NW - NK);
    int d1  = cs1 - cs0;                        // 0 or 1; 1 for bw in 1..10
    int ktb = (rs - (h0 - 3)) * 25 + (cs0 - (w0 - 3));

    // ---- block-level cd/mask/rpb staging (14x22 tile, 308 elems) ----
    const float* cdb = cd   + (size_t)b * NHW;
    const float* msb = mask + (size_t)b * NHW;
    for (int e = tid; e < 308; e += 256) {
        int r = e / 22, c = e - r * 22;
        int gr = min(max(h0 - 3 + r, 0), NH - 1);
        int gc = min(max(w0 - 3 + c, 0), NW - 1);
        cdt[r * 25 + c] = cdb[gr * NW + gc];
        mt [r * 25 + c] = msb[gr * NW + gc];
    }
    if (tid < 169) rpbt[tid] = rpb[tid];

    // ---- k staging slots: 308 elems (14x22), 5 rounds of 64 ----
    int soff[5], slds[5];
#pragma unroll
    for (int s = 0; s < 5; ++s) {
        int e = lane + 64 * s;
        int r = e / 22, c = e - r * 22;
        int gr = min(max(h0 - 3 + r, 0), NH - 1);
        int gc = min(max(w0 - 3 + c, 0), NW - 1);
        bool act = e < 308;
        soff[s] = act ? (gr * NW + gc) : 0;     // safe addr for inactive
        slds[s] = act ? (r * 25 + c) : 348;     // dummy slot for inactive
    }

    const float* kb = kbuf + (size_t)(b * NC + g * 16) * NHW;
    const float* qb = qbuf + (size_t)(b * NC + g * 16) * NHW + h * NW + wpx;

    float at0[49], at1[49];
#pragma unroll
    for (int n = 0; n < 49; ++n) { at0[n] = 0.f; at1[n] = 0.f; }

    float* k0 = &kst[g][0][0];
    float* k1 = &kst[g][1][0];

    auto run = [&](auto edgec) {
        constexpr bool EDGE = decltype(edgec)::value;
        float st[5];
#pragma unroll
        for (int s = 0; s < 5; ++s) st[s] = kb[soff[s]];
#pragma unroll
        for (int s = 0; s < 5; ++s) k0[slds[s]] = st[s];
        float2 qA = *(const float2*)qb;
        float2 qB = *(const float2*)(qb + NHW);
        for (int i = 0; i < 16; ++i) {
            if (i + 1 < 16) {
                const float* kb2 = kb + (size_t)(i + 1) * NHW;
#pragma unroll
                for (int s = 0; s < 5; ++s) st[s] = kb2[soff[s]];
            }
            float2 q = qA; qA = qB;
            if (i + 2 < 16) qB = *(const float2*)(qb + (size_t)(i + 2) * NHW);
            const float* kt = ((i & 1) ? k1 : k0) + ktb;
#pragma unroll
            for (int r = 0; r < 7; ++r) {
                const float* kr = kt + r * 25;
                float v[8];
#pragma unroll
                for (int j = 0; j < 8; ++j) v[j] = kr[j];
#pragma unroll
                for (int j = 0; j < 7; ++j)
                    at0[r * 7 + j] = fmaf(q.x, v[j], at0[r * 7 + j]);
#pragma unroll
                for (int j = 0; j < 7; ++j) {
                    float u;
                    if constexpr (EDGE) u = d1 ? v[j + 1] : v[j];
                    else                u = v[j + 1];
                    at1[r * 7 + j] = fmaf(q.y, u, at1[r * 7 + j]);
                }
            }
            if (i + 1 < 16) {
                float* nk = (i & 1) ? k0 : k1;
#pragma unroll
                for (int s = 0; s < 5; ++s) nk[slds[s]] = st[s];
            }
        }
    };
    if (bw == 0 || bw == 11) run(TrueC{}); else run(FalseC{});

    // ---- combine 4 quarters via xch[n][pp][lane] (conflict-free) ----
    __syncthreads();                       // also publishes cdt/mt/rpbt
    if (g == 3) {
#pragma unroll
        for (int n = 0; n < 49; ++n) {
            xch[n][0][lane] = at0[n]; xch[n][1][lane] = at1[n];
        }
    }
    __syncthreads();
    if (g == 2) {
#pragma unroll
        for (int n = 0; n < 49; ++n) {
            xch[n][0][lane] += at0[n]; xch[n][1][lane] += at1[n];
        }
    }
    __syncthreads();
    if (g == 0) {
#pragma unroll
        for (int n = 0; n < 49; ++n) {
            xch[n][0][lane] += at0[n]; xch[n][1][lane] += at1[n];
        }
    }
    __syncthreads();
    int pr  = 6 - (h - rs);
    int pc0 = 6 - (wpx - cs0);
    int pc1 = 6 - (wpx + 1 - cs1);
    if (g == 1) {
#pragma unroll
        for (int n = 0; n < 49; ++n) {
            at0[n] += xch[n][0][lane]; at1[n] += xch[n][1][lane];
        }
#pragma unroll
        for (int r = 0; r < 7; ++r)
#pragma unroll
            for (int j = 0; j < 7; ++j) {
                at0[r * 7 + j] += rpbt[(pr + r) * 13 + pc0 + j];
                at1[r * 7 + j] += rpbt[(pr + r) * 13 + pc1 + j];
            }
#pragma unroll
        for (int n = 0; n < 49; ++n) {
            xch[n][0][lane] = at0[n]; xch[n][1][lane] = at1[n];
        }
    }
    __syncthreads();
    if (g == 0) {
#pragma unroll
        for (int n = 0; n < 49; ++n) {
            at0[n] = xch[n][0][lane]; at1[n] = xch[n][1][lane];
        }
    }
    if (g >= 2) return;

    // ---- softmax (quarters 0/1 hold identical full logits) ----
    float mx0 = -1e30f, mx1 = -1e30f;
#pragma unroll
    for (int n = 0; n < 49; ++n) {
        mx0 = fmaxf(mx0, at0[n]); mx1 = fmaxf(mx1, at1[n]);
    }
    float sm0 = 0.f, sm1 = 0.f;
#pragma unroll
    for (int n = 0; n < 49; ++n) {
        at0[n] = __expf(at0[n] - mx0); sm0 += at0[n];
        at1[n] = __expf(at1[n] - mx1); sm1 += at1[n];
    }

    // ---- aggregate: quarter 0 -> cd, quarter 1 -> mask (shared window) ----
    const float* vt = (g ? mt : cdt) + ktb;
    float sv0 = 0.f, sv1 = 0.f;
#pragma unroll
    for (int r = 0; r < 7; ++r) {
        const float* vr = vt + r * 25;
        float v[8];
#pragma unroll
        for (int j = 0; j < 8; ++j) v[j] = vr[j];
#pragma unroll
        for (int j = 0; j < 7; ++j) {
            sv0 = fmaf(at0[r * 7 + j], v[j], sv0);
            float u = d1 ? v[j + 1] : v[j];
            sv1 = fmaf(at1[r * 7 + j], u, sv1);
        }
    }
    sv0 /= sm0; sv1 /= sm1;

    int p = b * NHW + h * NW + wpx;
    float2 sdv = *(const float2*)(sd + p);
    int ci = (ty + 3) * 25 + (2 * tx + 3);
    float mc0 = mt[ci], mc1 = mt[ci + 1];
    if (g == 0) {
        float cdc0 = cdt[ci], cdc1 = cdt[ci + 1];
        float co0 = sv0 * mc0 + cdc0 * (1.f - mc0);
        float co1 = sv1 * mc1 + cdc1 * (1.f - mc1);
        if (sdv.x > 0.f) co0 = sdv.x;
        if (sdv.y > 0.f) co1 = sdv.y;
        *(float2*)(out_cd + p) = make_float2(co0, co1);
    } else {
        float o0 = (sdv.x > 0.f) ? mc0 : sv0;
        float o1 = (sdv.y > 0.f) ? mc1 : sv1;
        *(float2*)(out_mask + p) = make_float2(o0, o1);
    }
}

extern "C" void kernel_launch(void* const* d_in, const int* in_sizes, int n_in,
                              void* d_out, int out_size, void* d_ws, size_t ws_size,
                              hipStream_t stream) {
    const float* g      = (const float*)d_in[0];
    const float* cd     = (const float*)d_in[1];
    const float* sd     = (const float*)d_in[2];
    const float* mask   = (const float*)d_in[3];
    const float* ln_w   = (const float*)d_in[4];
    const float* ln_b   = (const float*)d_in[5];
    const float* conv_w = (const float*)d_in[6];
    const float* conv_b = (const float*)d_in[7];
    const float* rpb    = (const float*)d_in[8];

    float* out  = (float*)d_out;                 // [cd_out | mask_out]
    float* qbuf = (float*)d_ws;                  // NB*NC*NHW floats
    float* kbuf = qbuf + (size_t)NB * NC * NHW;  // NB*NC*NHW floats

    qk_gemm<<<dim3(NPIX / 128), dim3(256), 0, stream>>>(
        g, cd, mask, ln_w, ln_b, conv_w, conv_b, qbuf, kbuf);
    attn_tile<<<dim3(NB * 24 * 12), dim3(256), 0, stream>>>(
        qbuf, kbuf, cd, sd, mask, rpb, out, out + NPIX);
}

// Round 8
// 136.045 us; speedup vs baseline: 15.7099x; 1.0297x over previous
//
#include <hip/hip_runtime.h>

constexpr int NB = 2;
constexpr int NC = 64;
constexpr int NH = 192;
constexpr int NW = 192;
constexpr int NK = 7;
constexpr int NHW = NH * NW;          // 36864
constexpr int NPIX = NB * NHW;        // 73728
constexpr float EPS = 1e-6f;

// ---------------------------------------------------------------------------
// Kernel 1: layernorm + 1x1 conv as LDS-tiled GEMM.  EXACT R4/R8 version —
// the allocator-stable 68-VGPR shape that measured 135.0 µs total. The WTc
// staging is deliberately the original if(tid<128) serial form: R11's
// "neutral" parallelization coincided with a +5 µs regression; reverted.
// ---------------------------------------------------------------------------
__global__ __launch_bounds__(256) void qk_gemm(
    const float* __restrict__ g, const float* __restrict__ cd,
    const float* __restrict__ mask,
    const float* __restrict__ ln_w, const float* __restrict__ ln_b,
    const float* __restrict__ conv_w, const float* __restrict__ conv_b,
    float* __restrict__ qbuf, float* __restrict__ kbuf)
{
    __shared__ float Z[65][128];
    __shared__ float WTc[33][128];

    int tid = threadIdx.x;
    int p0 = blockIdx.x * 128;
    int b  = p0 / NHW;
    int hw0 = p0 - b * NHW;

    int px = tid >> 1;
    int hf = tid & 1;
    const float* gp = g + (size_t)(b * NC + hf * 32) * NHW + (hw0 + px);
    float vals[32];
    float s = 0.f, sq = 0.f;
#pragma unroll
    for (int j = 0; j < 32; ++j) {
        float v = gp[(size_t)j * NHW];
        vals[j] = v; s += v; sq += v * v;
    }
    s  += __shfl_xor(s, 1);
    sq += __shfl_xor(sq, 1);
    float mu   = s * (1.f / 64.f);
    float rstd = rsqrtf(sq * (1.f / 64.f) - mu * mu + EPS);
#pragma unroll
    for (int j = 0; j < 32; ++j) {
        int c = hf * 32 + j;
        Z[c][px] = (vals[j] - mu) * rstd * ln_w[c] + ln_b[c];
    }
    if (hf) Z[64][px] = cd[p0 + px];

    int og = tid >> 4;
    int pg = tid & 15;
    float acc[8][8];
#pragma unroll
    for (int oi = 0; oi < 8; ++oi)
#pragma unroll
        for (int pj = 0; pj < 8; ++pj) acc[oi][pj] = 0.f;

    for (int cc = 0; cc < 65; cc += 33) {
        int nr = (65 - cc < 33) ? (65 - cc) : 33;
        __syncthreads();
        if (tid < 128) {
            int o = tid;
            for (int r = 0; r < nr; ++r)
                WTc[r][o] = conv_w[o * 65 + cc + r];
        }
        __syncthreads();
        for (int r = 0; r < nr; ++r) {
            float4 w0 = *(const float4*)&WTc[r][8 * og];
            float4 w1 = *(const float4*)&WTc[r][8 * og + 4];
            float4 z0 = *(const float4*)&Z[cc + r][8 * pg];
            float4 z1 = *(const float4*)&Z[cc + r][8 * pg + 4];
            float w8[8] = {w0.x, w0.y, w0.z, w0.w, w1.x, w1.y, w1.z, w1.w};
            float z8[8] = {z0.x, z0.y, z0.z, z0.w, z1.x, z1.y, z1.z, z1.w};
#pragma unroll
            for (int oi = 0; oi < 8; ++oi)
#pragma unroll
                for (int pj = 0; pj < 8; ++pj)
                    acc[oi][pj] = fmaf(w8[oi], z8[pj], acc[oi][pj]);
        }
    }

    int o0  = og * 8;
    int pxb = pg * 8;
    float4 ba = *(const float4*)&conv_b[o0];
    float4 bb = *(const float4*)&conv_b[o0 + 4];
    float bia[8] = {ba.x, ba.y, ba.z, ba.w, bb.x, bb.y, bb.z, bb.w};
    bool isq = (o0 < 64);
    float m8[8];
    if (!isq) {
        float4 ma = *(const float4*)&mask[p0 + pxb];
        float4 mc = *(const float4*)&mask[p0 + pxb + 4];
        m8[0]=ma.x; m8[1]=ma.y; m8[2]=ma.z; m8[3]=ma.w;
        m8[4]=mc.x; m8[5]=mc.y; m8[6]=mc.z; m8[7]=mc.w;
    }
    float* base = isq ? (qbuf + (size_t)(b * NC + o0) * NHW + hw0 + pxb)
                      : (kbuf + (size_t)(b * NC + o0 - 64) * NHW + hw0 + pxb);
#pragma unroll
    for (int oi = 0; oi < 8; ++oi) {
        float v[8];
#pragma unroll
        for (int pj = 0; pj < 8; ++pj) {
            float t = acc[oi][pj] + bia[oi];
            v[pj] = isq ? t : t * m8[pj];
        }
        float* dst = base + (size_t)oi * NHW;
        *(float4*)&dst[0] = make_float4(v[0], v[1], v[2], v[3]);
        *(float4*)&dst[4] = make_float4(v[4], v[5], v[6], v[7]);
    }
}

// ---------------------------------------------------------------------------
// Kernel 2 (v8, byte-identical to R8 — measured ~39 µs): 2-pixel horizontal
// blocking, 4 channel-quarter waves, conflict-free xch combine, XCD swizzle.
// ---------------------------------------------------------------------------
struct TrueC  { static constexpr bool value = true;  };
struct FalseC { static constexpr bool value = false; };

__global__ __launch_bounds__(256) void attn_tile(
    const float* __restrict__ qbuf, const float* __restrict__ kbuf,
    const float* __restrict__ cd, const float* __restrict__ sd,
    const float* __restrict__ mask, const float* __restrict__ rpb,
    float* __restrict__ out_cd, float* __restrict__ out_mask)
{
    __shared__ float kst[4][2][350];   // 11.2 KB: 4 waves x 2 bufs x 14x25
    __shared__ float xch[49][2][64];   // 24.5 KB, conflict-free combine
    __shared__ float cdt[350];         // 14 x 22 @ pitch 25
    __shared__ float mt [350];
    __shared__ float rpbt[169];        // total ~38.8 KB

    int tid  = threadIdx.x;
    int g    = tid >> 6;       // channel quarter 0..3 (16 ch each)
    int lane = tid & 63;
    int tx   = lane & 7;       // col-pair index
    int ty   = lane >> 3;      // row 0..7

    // XCD swizzle (proven 4x FETCH cut): contiguous 72-tile slab per XCD.
    int bid = blockIdx.x;
    int swz = (bid & 7) * 72 + (bid >> 3);
    int bw = swz % 12;
    int t2 = swz / 12;
    int bh = t2 % 24;
    int b  = t2 / 24;
    int w0 = bw * 16, h0 = bh * 8;

    int h   = h0 + ty;
    int wpx = w0 + 2 * tx;                      // pixel0; pixel1 = wpx+1
    int rs  = min(max(h - 3, 0), NH - NK);
    int cs0 = min(max(wpx - 3, 0), NW - NK);
    int cs1 = min(max(wpx - 2, 0), NW - NK);
    int d1  = cs1 - cs0;                        // 0 or 1; 1 for bw in 1..10
    int ktb = (rs - (h0 - 3)) * 25 + (cs0 - (w0 - 3));

    // ---- block-level cd/mask/rpb staging (14x22 tile, 308 elems) ----
    const float* cdb = cd   + (size_t)b * NHW;
    const float* msb = mask + (size_t)b * NHW;
    for (int e = tid; e < 308; e += 256) {
        int r = e / 22, c = e - r * 22;
        int gr = min(max(h0 - 3 + r, 0), NH - 1);
        int gc = min(max(w0 - 3 + c, 0), NW - 1);
        cdt[r * 25 + c] = cdb[gr * NW + gc];
        mt [r * 25 + c] = msb[gr * NW + gc];
    }
    if (tid < 169) rpbt[tid] = rpb[tid];

    // ---- k staging slots: 308 elems (14x22), 5 rounds of 64 ----
    int soff[5], slds[5];
#pragma unroll
    for (int s = 0; s < 5; ++s) {
        int e = lane + 64 * s;
        int r = e / 22, c = e - r * 22;
        int gr = min(max(h0 - 3 + r, 0), NH - 1);
        int gc = min(max(w0 - 3 + c, 0), NW - 1);
        bool act = e < 308;
        soff[s] = act ? (gr * NW + gc) : 0;     // safe addr for inactive
        slds[s] = act ? (r * 25 + c) : 348;     // dummy slot for inactive
    }

    const float* kb = kbuf + (size_t)(b * NC + g * 16) * NHW;
    const float* qb = qbuf + (size_t)(b * NC + g * 16) * NHW + h * NW + wpx;

    float at0[49], at1[49];
#pragma unroll
    for (int n = 0; n < 49; ++n) { at0[n] = 0.f; at1[n] = 0.f; }

    float* k0 = &kst[g][0][0];
    float* k1 = &kst[g][1][0];

    auto run = [&](auto edgec) {
        constexpr bool EDGE = decltype(edgec)::value;
        float st[5];
#pragma unroll
        for (int s = 0; s < 5; ++s) st[s] = kb[soff[s]];
#pragma unroll
        for (int s = 0; s < 5; ++s) k0[slds[s]] = st[s];
        float2 qA = *(const float2*)qb;
        float2 qB = *(const float2*)(qb + NHW);
        for (int i = 0; i < 16; ++i) {
            if (i + 1 < 16) {
                const float* kb2 = kb + (size_t)(i + 1) * NHW;
#pragma unroll
                for (int s = 0; s < 5; ++s) st[s] = kb2[soff[s]];
            }
            float2 q = qA; qA = qB;
            if (i + 2 < 16) qB = *(const float2*)(qb + (size_t)(i + 2) * NHW);
            const float* kt = ((i & 1) ? k1 : k0) + ktb;
#pragma unroll
            for (int r = 0; r < 7; ++r) {
                const float* kr = kt + r * 25;
                float v[8];
#pragma unroll
                for (int j = 0; j < 8; ++j) v[j] = kr[j];
#pragma unroll
                for (int j = 0; j < 7; ++j)
                    at0[r * 7 + j] = fmaf(q.x, v[j], at0[r * 7 + j]);
#pragma unroll
                for (int j = 0; j < 7; ++j) {
                    float u;
                    if constexpr (EDGE) u = d1 ? v[j + 1] : v[j];
                    else                u = v[j + 1];
                    at1[r * 7 + j] = fmaf(q.y, u, at1[r * 7 + j]);
                }
            }
            if (i + 1 < 16) {
                float* nk = (i & 1) ? k0 : k1;
#pragma unroll
                for (int s = 0; s < 5; ++s) nk[slds[s]] = st[s];
            }
        }
    };
    if (bw == 0 || bw == 11) run(TrueC{}); else run(FalseC{});

    // ---- combine 4 quarters via xch[n][pp][lane] (conflict-free) ----
    __syncthreads();                       // also publishes cdt/mt/rpbt
    if (g == 3) {
#pragma unroll
        for (int n = 0; n < 49; ++n) {
            xch[n][0][lane] = at0[n]; xch[n][1][lane] = at1[n];
        }
    }
    __syncthreads();
    if (g == 2) {
#pragma unroll
        for (int n = 0; n < 49; ++n) {
            xch[n][0][lane] += at0[n]; xch[n][1][lane] += at1[n];
        }
    }
    __syncthreads();
    if (g == 0) {
#pragma unroll
        for (int n = 0; n < 49; ++n) {
            xch[n][0][lane] += at0[n]; xch[n][1][lane] += at1[n];
        }
    }
    __syncthreads();
    int pr  = 6 - (h - rs);
    int pc0 = 6 - (wpx - cs0);
    int pc1 = 6 - (wpx + 1 - cs1);
    if (g == 1) {
#pragma unroll
        for (int n = 0; n < 49; ++n) {
            at0[n] += xch[n][0][lane]; at1[n] += xch[n][1][lane];
        }
#pragma unroll
        for (int r = 0; r < 7; ++r)
#pragma unroll
            for (int j = 0; j < 7; ++j) {
                at0[r * 7 + j] += rpbt[(pr + r) * 13 + pc0 + j];
                at1[r * 7 + j] += rpbt[(pr + r) * 13 + pc1 + j];
            }
#pragma unroll
        for (int n = 0; n < 49; ++n) {
            xch[n][0][lane] = at0[n]; xch[n][1][lane] = at1[n];
        }
    }
    __syncthreads();
    if (g == 0) {
#pragma unroll
        for (int n = 0; n < 49; ++n) {
            at0[n] = xch[n][0][lane]; at1[n] = xch[n][1][lane];
        }
    }
    if (g >= 2) return;

    // ---- softmax (quarters 0/1 hold identical full logits) ----
    float mx0 = -1e30f, mx1 = -1e30f;
#pragma unroll
    for (int n = 0; n < 49; ++n) {
        mx0 = fmaxf(mx0, at0[n]); mx1 = fmaxf(mx1, at1[n]);
    }
    float sm0 = 0.f, sm1 = 0.f;
#pragma unroll
    for (int n = 0; n < 49; ++n) {
        at0[n] = __expf(at0[n] - mx0); sm0 += at0[n];
        at1[n] = __expf(at1[n] - mx1); sm1 += at1[n];
    }

    // ---- aggregate: quarter 0 -> cd, quarter 1 -> mask (shared window) ----
    const float* vt = (g ? mt : cdt) + ktb;
    float sv0 = 0.f, sv1 = 0.f;
#pragma unroll
    for (int r = 0; r < 7; ++r) {
        const float* vr = vt + r * 25;
        float v[8];
#pragma unroll
        for (int j = 0; j < 8; ++j) v[j] = vr[j];
#pragma unroll
        for (int j = 0; j < 7; ++j) {
            sv0 = fmaf(at0[r * 7 + j], v[j], sv0);
            float u = d1 ? v[j + 1] : v[j];
            sv1 = fmaf(at1[r * 7 + j], u, sv1);
        }
    }
    sv0 /= sm0; sv1 /= sm1;

    int p = b * NHW + h * NW + wpx;
    float2 sdv = *(const float2*)(sd + p);
    int ci = (ty + 3) * 25 + (2 * tx + 3);
    float mc0 = mt[ci], mc1 = mt[ci + 1];
    if (g == 0) {
        float cdc0 = cdt[ci], cdc1 = cdt[ci + 1];
        float co0 = sv0 * mc0 + cdc0 * (1.f - mc0);
        float co1 = sv1 * mc1 + cdc1 * (1.f - mc1);
        if (sdv.x > 0.f) co0 = sdv.x;
        if (sdv.y > 0.f) co1 = sdv.y;
        *(float2*)(out_cd + p) = make_float2(co0, co1);
    } else {
        float o0 = (sdv.x > 0.f) ? mc0 : sv0;
        float o1 = (sdv.y > 0.f) ? mc1 : sv1;
        *(float2*)(out_mask + p) = make_float2(o0, o1);
    }
}

extern "C" void kernel_launch(void* const* d_in, const int* in_sizes, int n_in,
                              void* d_out, int out_size, void* d_ws, size_t ws_size,
                              hipStream_t stream) {
    const float* g      = (const float*)d_in[0];
    const float* cd     = (const float*)d_in[1];
    const float* sd     = (const float*)d_in[2];
    const float* mask   = (const float*)d_in[3];
    const float* ln_w   = (const float*)d_in[4];
    const float* ln_b   = (const float*)d_in[5];
    const float* conv_w = (const float*)d_in[6];
    const float* conv_b = (const float*)d_in[7];
    const float* rpb    = (const float*)d_in[8];

    float* out  = (float*)d_out;                 // [cd_out | mask_out]
    float* qbuf = (float*)d_ws;                  // NB*NC*NHW floats
    float* kbuf = qbuf + (size_t)NB * NC * NHW;  // NB*NC*NHW floats

    qk_gemm<<<dim3(NPIX / 128), dim3(256), 0, stream>>>(
        g, cd, mask, ln_w, ln_b, conv_w, conv_b, qbuf, kbuf);
    attn_tile<<<dim3(NB * 24 * 12), dim3(256), 0, stream>>>(
        qbuf, kbuf, cd, sd, mask, rpb, out, out + NPIX);
}

// Round 9
// 132.386 us; speedup vs baseline: 16.1441x; 1.0276x over previous
//
#include <hip/hip_runtime.h>

constexpr int NB = 2;
constexpr int NC = 64;
constexpr int NH = 192;
constexpr int NW = 192;
constexpr int NK = 7;
constexpr int NHW = NH * NW;          // 36864
constexpr int NPIX = NB * NHW;        // 73728
constexpr float EPS = 1e-6f;

// ---------------------------------------------------------------------------
// Kernel 1: layernorm + 1x1 conv as LDS-tiled GEMM.  EXACT R4/R8/R12 version
// (allocator-stable 68-VGPR shape; serial if(tid<128) WTc staging kept —
// R11's parallelized variant coincided with a regression).
// ---------------------------------------------------------------------------
__global__ __launch_bounds__(256) void qk_gemm(
    const float* __restrict__ g, const float* __restrict__ cd,
    const float* __restrict__ mask,
    const float* __restrict__ ln_w, const float* __restrict__ ln_b,
    const float* __restrict__ conv_w, const float* __restrict__ conv_b,
    float* __restrict__ qbuf, float* __restrict__ kbuf)
{
    __shared__ float Z[65][128];
    __shared__ float WTc[33][128];

    int tid = threadIdx.x;
    int p0 = blockIdx.x * 128;
    int b  = p0 / NHW;
    int hw0 = p0 - b * NHW;

    int px = tid >> 1;
    int hf = tid & 1;
    const float* gp = g + (size_t)(b * NC + hf * 32) * NHW + (hw0 + px);
    float vals[32];
    float s = 0.f, sq = 0.f;
#pragma unroll
    for (int j = 0; j < 32; ++j) {
        float v = gp[(size_t)j * NHW];
        vals[j] = v; s += v; sq += v * v;
    }
    s  += __shfl_xor(s, 1);
    sq += __shfl_xor(sq, 1);
    float mu   = s * (1.f / 64.f);
    float rstd = rsqrtf(sq * (1.f / 64.f) - mu * mu + EPS);
#pragma unroll
    for (int j = 0; j < 32; ++j) {
        int c = hf * 32 + j;
        Z[c][px] = (vals[j] - mu) * rstd * ln_w[c] + ln_b[c];
    }
    if (hf) Z[64][px] = cd[p0 + px];

    int og = tid >> 4;
    int pg = tid & 15;
    float acc[8][8];
#pragma unroll
    for (int oi = 0; oi < 8; ++oi)
#pragma unroll
        for (int pj = 0; pj < 8; ++pj) acc[oi][pj] = 0.f;

    for (int cc = 0; cc < 65; cc += 33) {
        int nr = (65 - cc < 33) ? (65 - cc) : 33;
        __syncthreads();
        if (tid < 128) {
            int o = tid;
            for (int r = 0; r < nr; ++r)
                WTc[r][o] = conv_w[o * 65 + cc + r];
        }
        __syncthreads();
        for (int r = 0; r < nr; ++r) {
            float4 w0 = *(const float4*)&WTc[r][8 * og];
            float4 w1 = *(const float4*)&WTc[r][8 * og + 4];
            float4 z0 = *(const float4*)&Z[cc + r][8 * pg];
            float4 z1 = *(const float4*)&Z[cc + r][8 * pg + 4];
            float w8[8] = {w0.x, w0.y, w0.z, w0.w, w1.x, w1.y, w1.z, w1.w};
            float z8[8] = {z0.x, z0.y, z0.z, z0.w, z1.x, z1.y, z1.z, z1.w};
#pragma unroll
            for (int oi = 0; oi < 8; ++oi)
#pragma unroll
                for (int pj = 0; pj < 8; ++pj)
                    acc[oi][pj] = fmaf(w8[oi], z8[pj], acc[oi][pj]);
        }
    }

    int o0  = og * 8;
    int pxb = pg * 8;
    float4 ba = *(const float4*)&conv_b[o0];
    float4 bb = *(const float4*)&conv_b[o0 + 4];
    float bia[8] = {ba.x, ba.y, ba.z, ba.w, bb.x, bb.y, bb.z, bb.w};
    bool isq = (o0 < 64);
    float m8[8];
    if (!isq) {
        float4 ma = *(const float4*)&mask[p0 + pxb];
        float4 mc = *(const float4*)&mask[p0 + pxb + 4];
        m8[0]=ma.x; m8[1]=ma.y; m8[2]=ma.z; m8[3]=ma.w;
        m8[4]=mc.x; m8[5]=mc.y; m8[6]=mc.z; m8[7]=mc.w;
    }
    float* base = isq ? (qbuf + (size_t)(b * NC + o0) * NHW + hw0 + pxb)
                      : (kbuf + (size_t)(b * NC + o0 - 64) * NHW + hw0 + pxb);
#pragma unroll
    for (int oi = 0; oi < 8; ++oi) {
        float v[8];
#pragma unroll
        for (int pj = 0; pj < 8; ++pj) {
            float t = acc[oi][pj] + bia[oi];
            v[pj] = isq ? t : t * m8[pj];
        }
        float* dst = base + (size_t)oi * NHW;
        *(float4*)&dst[0] = make_float4(v[0], v[1], v[2], v[3]);
        *(float4*)&dst[4] = make_float4(v[4], v[5], v[6], v[7]);
    }
}

// ---------------------------------------------------------------------------
// Kernel 2 (v9): R8's core loop byte-identical; EPILOGUE restructured into
// two parallel reduction chains over the xch halves:
//   px0 chain (xch[.][0]): g1 w -> g2 += -> g3 += -> g0 reads (+own)
//   px1 chain (xch[.][1]): g0 w -> g3 += -> g2 += -> g1 reads (+own)
// 2 waves active per round on disjoint buffers; rounds 5->4, barriers 5->3,
// per-round traffic halved (49/lane), softmax once per pixel (49 exp/wave).
// g0 outputs cd&mask @px0; g1 outputs cd&mask @px1.
// ---------------------------------------------------------------------------
struct TrueC  { static constexpr bool value = true;  };
struct FalseC { static constexpr bool value = false; };

__global__ __launch_bounds__(256) void attn_tile(
    const float* __restrict__ qbuf, const float* __restrict__ kbuf,
    const float* __restrict__ cd, const float* __restrict__ sd,
    const float* __restrict__ mask, const float* __restrict__ rpb,
    float* __restrict__ out_cd, float* __restrict__ out_mask)
{
    __shared__ float kst[4][2][350];   // 11.2 KB: 4 waves x 2 bufs x 14x25
    __shared__ float xch[49][2][64];   // 24.5 KB, conflict-free combine
    __shared__ float cdt[350];         // 14 x 22 @ pitch 25
    __shared__ float mt [350];
    __shared__ float rpbt[169];        // total ~38.8 KB

    int tid  = threadIdx.x;
    int g    = tid >> 6;       // channel quarter 0..3 (16 ch each)
    int lane = tid & 63;
    int tx   = lane & 7;       // col-pair index
    int ty   = lane >> 3;      // row 0..7

    // XCD swizzle (proven 4x FETCH cut): contiguous 72-tile slab per XCD.
    int bid = blockIdx.x;
    int swz = (bid & 7) * 72 + (bid >> 3);
    int bw = swz % 12;
    int t2 = swz / 12;
    int bh = t2 % 24;
    int b  = t2 / 24;
    int w0 = bw * 16, h0 = bh * 8;

    int h   = h0 + ty;
    int wpx = w0 + 2 * tx;                      // pixel0; pixel1 = wpx+1
    int rs  = min(max(h - 3, 0), NH - NK);
    int cs0 = min(max(wpx - 3, 0), NW - NK);
    int cs1 = min(max(wpx - 2, 0), NW - NK);
    int d1  = cs1 - cs0;                        // 0 or 1; 1 for bw in 1..10
    int ktb = (rs - (h0 - 3)) * 25 + (cs0 - (w0 - 3));

    // ---- block-level cd/mask/rpb staging (14x22 tile, 308 elems) ----
    const float* cdb = cd   + (size_t)b * NHW;
    const float* msb = mask + (size_t)b * NHW;
    for (int e = tid; e < 308; e += 256) {
        int r = e / 22, c = e - r * 22;
        int gr = min(max(h0 - 3 + r, 0), NH - 1);
        int gc = min(max(w0 - 3 + c, 0), NW - 1);
        cdt[r * 25 + c] = cdb[gr * NW + gc];
        mt [r * 25 + c] = msb[gr * NW + gc];
    }
    if (tid < 169) rpbt[tid] = rpb[tid];

    // ---- k staging slots: 308 elems (14x22), 5 rounds of 64 ----
    int soff[5], slds[5];
#pragma unroll
    for (int s = 0; s < 5; ++s) {
        int e = lane + 64 * s;
        int r = e / 22, c = e - r * 22;
        int gr = min(max(h0 - 3 + r, 0), NH - 1);
        int gc = min(max(w0 - 3 + c, 0), NW - 1);
        bool act = e < 308;
        soff[s] = act ? (gr * NW + gc) : 0;     // safe addr for inactive
        slds[s] = act ? (r * 25 + c) : 348;     // dummy slot for inactive
    }

    const float* kb = kbuf + (size_t)(b * NC + g * 16) * NHW;
    const float* qb = qbuf + (size_t)(b * NC + g * 16) * NHW + h * NW + wpx;

    float at0[49], at1[49];
#pragma unroll
    for (int n = 0; n < 49; ++n) { at0[n] = 0.f; at1[n] = 0.f; }

    float* k0 = &kst[g][0][0];
    float* k1 = &kst[g][1][0];

    auto run = [&](auto edgec) {
        constexpr bool EDGE = decltype(edgec)::value;
        float st[5];
#pragma unroll
        for (int s = 0; s < 5; ++s) st[s] = kb[soff[s]];
#pragma unroll
        for (int s = 0; s < 5; ++s) k0[slds[s]] = st[s];
        float2 qA = *(const float2*)qb;
        float2 qB = *(const float2*)(qb + NHW);
        for (int i = 0; i < 16; ++i) {
            if (i + 1 < 16) {
                const float* kb2 = kb + (size_t)(i + 1) * NHW;
#pragma unroll
                for (int s = 0; s < 5; ++s) st[s] = kb2[soff[s]];
            }
            float2 q = qA; qA = qB;
            if (i + 2 < 16) qB = *(const float2*)(qb + (size_t)(i + 2) * NHW);
            const float* kt = ((i & 1) ? k1 : k0) + ktb;
#pragma unroll
            for (int r = 0; r < 7; ++r) {
                const float* kr = kt + r * 25;
                float v[8];
#pragma unroll
                for (int j = 0; j < 8; ++j) v[j] = kr[j];
#pragma unroll
                for (int j = 0; j < 7; ++j)
                    at0[r * 7 + j] = fmaf(q.x, v[j], at0[r * 7 + j]);
#pragma unroll
                for (int j = 0; j < 7; ++j) {
                    float u;
                    if constexpr (EDGE) u = d1 ? v[j + 1] : v[j];
                    else                u = v[j + 1];
                    at1[r * 7 + j] = fmaf(q.y, u, at1[r * 7 + j]);
                }
            }
            if (i + 1 < 16) {
                float* nk = (i & 1) ? k0 : k1;
#pragma unroll
                for (int s = 0; s < 5; ++s) nk[slds[s]] = st[s];
            }
        }
    };
    if (bw == 0 || bw == 11) run(TrueC{}); else run(FalseC{});

    // ---- combine: two parallel chains over disjoint xch halves ----
    // R1: g1 seeds px0 chain, g0 seeds px1 chain
    if (g == 1) {
#pragma unroll
        for (int n = 0; n < 49; ++n) xch[n][0][lane] = at0[n];
    } else if (g == 0) {
#pragma unroll
        for (int n = 0; n < 49; ++n) xch[n][1][lane] = at1[n];
    }
    __syncthreads();                   // also publishes cdt/mt/rpbt
    // R2
    if (g == 2) {
#pragma unroll
        for (int n = 0; n < 49; ++n) xch[n][0][lane] += at0[n];
    } else if (g == 3) {
#pragma unroll
        for (int n = 0; n < 49; ++n) xch[n][1][lane] += at1[n];
    }
    __syncthreads();
    // R3
    if (g == 3) {
#pragma unroll
        for (int n = 0; n < 49; ++n) xch[n][0][lane] += at0[n];
    } else if (g == 2) {
#pragma unroll
        for (int n = 0; n < 49; ++n) xch[n][1][lane] += at1[n];
    }
    __syncthreads();
    if (g >= 2) return;                // no barriers below

    // R4: g0 -> full px0 logits; g1 -> full px1 logits
    int pr  = 6 - (h - rs);
    int pc0 = 6 - (wpx - cs0);
    int pc1 = 6 - (wpx + 1 - cs1);
    int pcx = (g == 0) ? pc0 : pc1;
    int dd  = (g == 0) ? 0 : d1;       // window shift for aggregation

    float aF[49];
    if (g == 0) {
#pragma unroll
        for (int n = 0; n < 49; ++n) aF[n] = at0[n] + xch[n][0][lane];
    } else {
#pragma unroll
        for (int n = 0; n < 49; ++n) aF[n] = at1[n] + xch[n][1][lane];
    }
#pragma unroll
    for (int r = 0; r < 7; ++r)
#pragma unroll
        for (int j = 0; j < 7; ++j)
            aF[r * 7 + j] += rpbt[(pr + r) * 13 + pcx + j];

    // ---- softmax (once per pixel) ----
    float mx = -1e30f;
#pragma unroll
    for (int n = 0; n < 49; ++n) mx = fmaxf(mx, aF[n]);
    float sm = 0.f;
#pragma unroll
    for (int n = 0; n < 49; ++n) {
        aF[n] = __expf(aF[n] - mx);
        sm += aF[n];
    }

    // ---- aggregate BOTH cd and mask for this wave's pixel ----
    const float* vtc = cdt + ktb;
    const float* vtm = mt  + ktb;
    float sc = 0.f, sv = 0.f;
#pragma unroll
    for (int r = 0; r < 7; ++r) {
        const float* vr = vtc + r * 25;
        const float* wr = vtm + r * 25;
        float v[8], w[8];
#pragma unroll
        for (int j = 0; j < 8; ++j) { v[j] = vr[j]; w[j] = wr[j]; }
#pragma unroll
        for (int j = 0; j < 7; ++j) {
            float a  = aF[r * 7 + j];
            float uC = dd ? v[j + 1] : v[j];
            float uM = dd ? w[j + 1] : w[j];
            sc = fmaf(a, uC, sc);
            sv = fmaf(a, uM, sv);
        }
    }
    sc /= sm; sv /= sm;

    int p = b * NHW + h * NW + wpx + g;          // g==0 -> px0, g==1 -> px1
    float sdc = sd[p];
    int ci = (ty + 3) * 25 + (2 * tx + 3) + g;
    float mc  = mt[ci];
    float cdc = cdt[ci];
    float co = sc * mc + cdc * (1.f - mc);
    if (sdc > 0.f) co = sdc;
    out_cd[p]   = co;
    out_mask[p] = (sdc > 0.f) ? mc : sv;
}

extern "C" void kernel_launch(void* const* d_in, const int* in_sizes, int n_in,
                              void* d_out, int out_size, void* d_ws, size_t ws_size,
                              hipStream_t stream) {
    const float* g      = (const float*)d_in[0];
    const float* cd     = (const float*)d_in[1];
    const float* sd     = (const float*)d_in[2];
    const float* mask   = (const float*)d_in[3];
    const float* ln_w   = (const float*)d_in[4];
    const float* ln_b   = (const float*)d_in[5];
    const float* conv_w = (const float*)d_in[6];
    const float* conv_b = (const float*)d_in[7];
    const float* rpb    = (const float*)d_in[8];

    float* out  = (float*)d_out;                 // [cd_out | mask_out]
    float* qbuf = (float*)d_ws;                  // NB*NC*NHW floats
    float* kbuf = qbuf + (size_t)NB * NC * NHW;  // NB*NC*NHW floats

    qk_gemm<<<dim3(NPIX / 128), dim3(256), 0, stream>>>(
        g, cd, mask, ln_w, ln_b, conv_w, conv_b, qbuf, kbuf);
    attn_tile<<<dim3(NB * 24 * 12), dim3(256), 0, stream>>>(
        qbuf, kbuf, cd, sd, mask, rpb, out, out + NPIX);
}